// Round 1
// 366.869 us; speedup vs baseline: 1.0174x; 1.0174x over previous
//
#include <hip/hip_runtime.h>

#define NN 50000
#define NE 800000
#define DIM 128
#define NB 128          // dst buckets for binned CSR build
#define CH 4096         // edges per binning block
#define CAP 8192        // slots per bucket (mean 6250, sd 79 -> +24 sigma)

typedef unsigned int uint;
typedef unsigned short ushort;
typedef __attribute__((ext_vector_type(8))) short v8s;
typedef __attribute__((ext_vector_type(4))) float v4f;

__device__ __forceinline__ ushort f2bf(float f) {
    union { float f; uint i; } c; c.f = f;
    const uint r = (c.i + 0x7fffu + ((c.i >> 16) & 1u)) >> 16;
    return (ushort)r;
}

// WT[m][n][k] = bf16(W[m][k][n]); m: 0,1 from W0, 2,3 from W1.
__global__ __launch_bounds__(256) void conv_wt(
    const float* __restrict__ W0, const float* __restrict__ W1,
    ushort* __restrict__ WT)
{
    const int t = blockIdx.x * 256 + threadIdx.x;
#pragma unroll
    for (int i = 0; i < 4; i++) {
        const int o = t * 4 + i;                    // 0 .. 65535
        const int m = o >> 14, rem = o & 16383;
        const int nrow = rem >> 7, k = rem & 127;
        const float* src = (m < 2) ? (W0 + (size_t)m * 16384)
                                   : (W1 + (size_t)(m - 2) * 16384);
        WT[o] = f2bf(src[k * 128 + nrow]);
    }
}

// ---------------- dual-relation MFMA GEMM ----------------
// Block 256 = 4 waves; wave w: rows [b*64+16w,+16) x 128 cols, both relations.
// A loaded once (f32 path converts in-register). Epilogue: LDS-staged
// coalesced bf16 store + fused el/er reduction.
__global__ __launch_bounds__(256) void gemm_dual(
    const ushort* __restrict__ hbf, const float* __restrict__ xf,
    const ushort* __restrict__ WT,
    const float* __restrict__ al, const float* __restrict__ ar,
    ushort* __restrict__ fg0, ushort* __restrict__ fg1,
    float* __restrict__ elb, int n, int is_f32)
{
    __shared__ ushort tile[64][136];
    const int tid = threadIdx.x;
    const int w = tid >> 6, lane = tid & 63;
    const int quad = lane >> 4, l16 = lane & 15;
    const int row0 = blockIdx.x * 64 + w * 16;

    int arow = row0 + l16;
    if (arow >= n) arow = n - 1;   // clamp; OOB rows never stored

    v8s afr[4];
    if (is_f32) {
        const float* ap = xf + (size_t)arow * DIM + quad * 8;
#pragma unroll
        for (int kt = 0; kt < 4; kt++) {
            const float4 a0 = *(const float4*)(ap + kt * 32);
            const float4 a1 = *(const float4*)(ap + kt * 32 + 4);
            ushort tmp[8] = { f2bf(a0.x), f2bf(a0.y), f2bf(a0.z), f2bf(a0.w),
                              f2bf(a1.x), f2bf(a1.y), f2bf(a1.z), f2bf(a1.w) };
            afr[kt] = *(const v8s*)tmp;
        }
    } else {
        const ushort* ap = hbf + (size_t)arow * DIM + quad * 8;
#pragma unroll
        for (int kt = 0; kt < 4; kt++) afr[kt] = *(const v8s*)(ap + kt * 32);
    }

    for (int rel = 0; rel < 2; rel++) {
        const ushort* bp = WT + (size_t)rel * DIM * DIM + (size_t)l16 * DIM + quad * 8;
        v4f acc[8];
#pragma unroll
        for (int nt = 0; nt < 8; nt++) acc[nt] = (v4f)0.0f;
#pragma unroll
        for (int kt = 0; kt < 4; kt++) {
#pragma unroll
            for (int nt = 0; nt < 8; nt++) {
                const v8s b = *(const v8s*)(bp + (size_t)nt * 16 * DIM + kt * 32);
                acc[nt] = __builtin_amdgcn_mfma_f32_16x16x32_bf16(afr[kt], b, acc[nt], 0, 0, 0);
            }
        }

        // el/er: partial dot per lane, reduce across l16 within quad rows
        const float* alr = al + rel * DIM;
        const float* arr = ar + rel * DIM;
        float pel[4][2], per2[4][2];
#pragma unroll
        for (int r = 0; r < 4; r++)
            pel[r][0] = pel[r][1] = per2[r][0] = per2[r][1] = 0.f;
#pragma unroll
        for (int nt = 0; nt < 8; nt++) {
            const int col = nt * 16 + l16;
            const float av = alr[col], rv = arr[col];
            const int head = nt >> 2;
#pragma unroll
            for (int r = 0; r < 4; r++) {
                pel[r][head] += acc[nt][r] * av;
                per2[r][head] += acc[nt][r] * rv;
            }
        }
#pragma unroll
        for (int o = 1; o < 16; o <<= 1) {
#pragma unroll
            for (int r = 0; r < 4; r++) {
#pragma unroll
                for (int h = 0; h < 2; h++) {
                    pel[r][h] += __shfl_xor(pel[r][h], o);
                    per2[r][h] += __shfl_xor(per2[r][h], o);
                }
            }
        }
        float* elp = elb + (size_t)rel * NN * 4;
        float* erp = elp + (size_t)NN * 2;
        if (l16 == 0) {
#pragma unroll
            for (int r = 0; r < 4; r++) {
                const int row = row0 + quad * 4 + r;
                if (row < n) {
#pragma unroll
                    for (int h = 0; h < 2; h++) {
                        elp[row * 2 + h] = pel[r][h];
                        erp[row * 2 + h] = per2[r][h];
                    }
                }
            }
        }

        // coalesced bf16 store via LDS
        __syncthreads();   // prior rel's tile reads done
        const int lr0 = w * 16 + quad * 4;
#pragma unroll
        for (int nt = 0; nt < 8; nt++) {
            const int col = nt * 16 + l16;
#pragma unroll
            for (int r = 0; r < 4; r++)
                tile[lr0 + r][col] = f2bf(acc[nt][r]);
        }
        __syncthreads();
        ushort* fgr = rel ? fg1 : fg0;
        const int srow = tid >> 2, ch = tid & 3;   // 64 rows x 4 chunks of 32
        const int grow = blockIdx.x * 64 + srow;
        if (grow < n) {
            const uint4* lp = (const uint4*)&tile[srow][ch * 32];
            uint4* gp = (uint4*)(fgr + (size_t)grow * DIM + ch * 32);
            gp[0] = lp[0];
            gp[1] = lp[1];
            gp[2] = lp[2];
            gp[3] = lp[3];
        }
    }
}

// ---------------- CSR build (fixed-capacity buckets) ----------------
__global__ __launch_bounds__(512) void init_gcur(int* __restrict__ gcur)
{
    const int i = threadIdx.x;
    gcur[i] = i * CAP;
}

// Pass A: bin edges by dst bucket; payload packed (dst<<16)|src.
__global__ __launch_bounds__(256) void bin_edges(
    const int* __restrict__ dst0, const int* __restrict__ dst1,
    const int* __restrict__ src0, const int* __restrict__ src1,
    int* __restrict__ gcur, uint* __restrict__ binned)
{
    __shared__ int hist[NB], ebase[NB], lcur[NB], gbase[NB], sc[NB];
    __shared__ uint stage[CH];
    const int bpset = (NE + CH - 1) / CH;
    const int bid = blockIdx.x;
    const int s = bid / bpset, cb = bid - s * bpset;
    const int* dstp = (s < 2) ? (dst0 + (size_t)s * NE) : (dst1 + (size_t)(s - 2) * NE);
    const int* srcp = (s < 2) ? (src0 + (size_t)s * NE) : (src1 + (size_t)(s - 2) * NE);
    const int e0 = cb * CH;
    const int t = threadIdx.x;

    if (t < NB) hist[t] = 0;
    __syncthreads();

    int myd[16], mys[16];
#pragma unroll
    for (int k = 0; k < 16; k++) {
        const int e = e0 + t + k * 256;
        if (e < NE) {
            const int d = dstp[e];
            myd[k] = d;
            mys[k] = srcp[e];
            atomicAdd(&hist[(d * NB) / NN], 1);
        } else myd[k] = -1;
    }
    __syncthreads();
    if (t < NB) sc[t] = hist[t];
    __syncthreads();
    for (int o = 1; o < NB; o <<= 1) {
        int tv = 0;
        if (t < NB && t >= o) tv = sc[t - o];
        __syncthreads();
        if (t < NB) sc[t] += tv;
        __syncthreads();
    }
    if (t < NB) {
        ebase[t] = sc[t] - hist[t];
        lcur[t]  = sc[t] - hist[t];
        gbase[t] = atomicAdd(&gcur[s * NB + t], hist[t]);
    }
    __syncthreads();
#pragma unroll
    for (int k = 0; k < 16; k++) {
        if (myd[k] >= 0) {
            const int b = (myd[k] * NB) / NN;
            const int p = atomicAdd(&lcur[b], 1);
            stage[p] = ((uint)myd[k] << 16) | (uint)mys[k];
        }
    }
    __syncthreads();
    const int total = ebase[NB - 1] + hist[NB - 1];
    for (int i = t; i < total; i += 256) {
        const uint v = stage[i];
        const int b = ((int)(v >> 16) * NB) / NN;
        binned[gbase[b] + (i - ebase[b])] = v;   // gbase is absolute (slotted)
    }
}

// post-scan: packed per-set bucket bases from gcur fill levels.
__global__ __launch_bounds__(64) void scan_buckets(
    const int* __restrict__ gcur, int* __restrict__ bbase, int* __restrict__ row)
{
    const int s = threadIdx.x;
    if (s < 4) {
        int acc = 0;
        for (int b = 0; b < NB; b++) {
            bbase[s * (NB + 1) + b] = acc;
            acc += gcur[s * NB + b] - (s * NB + b) * CAP;
        }
        bbase[s * (NB + 1) + NB] = acc;   // == NE
        row[s * (NN + 1) + NN] = NE;
    }
}

// Pass B: per (set,bucket): LDS degree count + scan -> row[] + ushort csr.
__global__ __launch_bounds__(256) void build_csr(
    const int* __restrict__ bbase, const uint* __restrict__ binned,
    int* __restrict__ row, ushort* __restrict__ csr_src)
{
    __shared__ int A[512], B[512], lcur[512];
    const int bid = blockIdx.x;
    const int s = bid >> 7, b = bid & (NB - 1);
    const int nb0 = (b * NN + NB - 1) / NB;
    int nb1 = ((b + 1) * NN + NB - 1) / NB;
    if (nb1 > NN) nb1 = NN;
    const int nloc = nb1 - nb0;
    const int jb = bbase[s * (NB + 1) + b], je = bbase[s * (NB + 1) + b + 1];
    const int cnt = je - jb;
    const uint* bslot = binned + (size_t)(s * NB + b) * CAP;
    const int t = threadIdx.x;

    A[t] = 0; A[t + 256] = 0;
    __syncthreads();
    for (int j = t; j < cnt; j += 256)
        atomicAdd(&A[(int)(bslot[j] >> 16) - nb0], 1);
    __syncthreads();
    const int c0 = A[t], c1 = A[t + 256];
    int* cur = A; int* nxt = B;
    for (int off = 1; off < 512; off <<= 1) {
        nxt[t]       = cur[t]       + ((t >= off)       ? cur[t - off]       : 0);
        nxt[t + 256] = cur[t + 256] + ((t + 256 >= off) ? cur[t + 256 - off] : 0);
        __syncthreads();
        int* tmp = cur; cur = nxt; nxt = tmp;
    }
    if (t < nloc) {
        const int v = jb + cur[t] - c0;
        lcur[t] = v;
        row[s * (NN + 1) + nb0 + t] = v;
    }
    if (t + 256 < nloc) {
        const int v = jb + cur[t + 256] - c1;
        lcur[t + 256] = v;
        row[s * (NN + 1) + nb0 + t + 256] = v;
    }
    __syncthreads();
    ushort* outp = csr_src + (size_t)s * NE;
    for (int j = t; j < cnt; j += 256) {
        const uint v = bslot[j];
        const int p = atomicAdd(&lcur[(int)(v >> 16) - nb0], 1);
        outp[p] = (ushort)(v & 0xffffu);
    }
}

__device__ __forceinline__ float elu(float v) { return v > 0.f ? v : expm1f(v); }
__device__ __forceinline__ float2 bfpair(uint u) {
    union { uint i; float f; } lo, hi;
    lo.i = u << 16;
    hi.i = u & 0xffff0000u;
    return make_float2(lo.f, hi.f);
}

// ---------------- dual-relation fused softmax + aggregate -------------------
// One wave per dst node. Inner loop processes TWO edges per iteration:
// lanes 0-31 handle edge tt, lanes 32-63 edge tt+1; each lane owns 4 output
// dims (4*(lane&31)..+3) loaded as one dwordx2 per edge. Offset+weight packed
// into one uint2 LDS entry -> 1 ds_read_b64 + 1 v_add + 1 global_load_dwordx2
// + 4 unpack + 4 fma per 2 edges (~half the issue slots of the 1-edge loop).
__global__ __launch_bounds__(256) void aggregate_dual(
    const int* __restrict__ row0, const ushort* __restrict__ csr0,
    const int* __restrict__ row1, const ushort* __restrict__ csr1,
    const float2* __restrict__ el0, const float2* __restrict__ er0,
    const float2* __restrict__ el1, const float2* __restrict__ er1,
    const ushort* __restrict__ fg0, const ushort* __restrict__ fg1,
    const float* __restrict__ bias0, const float* __restrict__ bias1,
    float* __restrict__ outf, ushort* __restrict__ outbf, int obf)
{
    __shared__ uint2 wo[4][2][64];   // [wid][head][edge] = {src<<8, w bits}
    const int wv = (blockIdx.x * 256 + threadIdx.x) >> 6;
    if (wv >= NN) return;
    const int lane = threadIdx.x & 63;
    const int wid = threadIdx.x >> 6;

    const int* rows[2] = {row0, row1};
    const ushort* csrs[2] = {csr0, csr1};
    const float2* els[2] = {el0, el1};
    const float2* ers[2] = {er0, er1};
    const ushort* fgs[2] = {fg0, fg1};
    const float* biases[2] = {bias0, bias1};

    const uint laneoff = (uint)(lane & 31) * 8u;  // byte offset of this lane's 4 dims
    const int head = (lane >> 4) & 1;             // dims 4*(lane&31) -> head (lane>>4)&1
    const int half = lane >> 5;                   // which of the 2 edges per iter

    float4 o4 = make_float4(0.f, 0.f, 0.f, 0.f);

#pragma unroll
    for (int rel = 0; rel < 2; rel++) {
        const int beg = rows[rel][wv], end = rows[rel][wv + 1];
        const int deg = end - beg;
        const float2 erd = ers[rel][wv];
        const char* fgb = (const char*)fgs[rel];
        const uint2* wop = &wo[wid][head][half];
        float4 a4 = make_float4(0.f, 0.f, 0.f, 0.f);

        if (deg <= 64) {
            uint sof = 0;
            float ex0 = 0.f, ex1 = 0.f;
            if (lane < deg) {
                const int s = csrs[rel][beg + lane];
                const float2 e = els[rel][s];
                float e0 = e.x + erd.x, e1 = e.y + erd.y;
                e0 = e0 > 0.f ? e0 : 0.2f * e0;
                e1 = e1 > 0.f ? e1 : 0.2f * e1;
                ex0 = __expf(e0);
                ex1 = __expf(e1);
                sof = (uint)s << 8;
            }
            float den0 = ex0, den1 = ex1;
            for (int o = 32; o > 0; o >>= 1) {
                den0 += __shfl_xor(den0, o);
                den1 += __shfl_xor(den1, o);
            }
            const float inv0 = 1.0f / den0, inv1 = 1.0f / den1;
            wo[wid][0][lane] = make_uint2(sof, __float_as_uint(ex0 * inv0));
            wo[wid][1][lane] = make_uint2(sof, __float_as_uint(ex1 * inv1));
            const int dp = (deg + 1) & ~1;   // pad slot has w=0, sof=0
#pragma unroll 4
            for (int tt = 0; tt < dp; tt += 2) {
                const uint2 ow = wop[tt];
                const float wgt = __uint_as_float(ow.y);
                const uint2 u = *(const uint2*)(fgb + (ow.x + laneoff));
                const float2 lo = bfpair(u.x), hi = bfpair(u.y);
                a4.x += lo.x * wgt; a4.y += lo.y * wgt;
                a4.z += hi.x * wgt; a4.w += hi.y * wgt;
            }
        } else {
            // (statistically dead for Poisson(16) degrees; kept for safety)
            float den0 = 0.f, den1 = 0.f;
            for (int c0 = beg; c0 < end; c0 += 64) {
                const int j = c0 + lane;
                if (j < end) {
                    const float2 e = els[rel][csrs[rel][j]];
                    float e0 = e.x + erd.x, e1 = e.y + erd.y;
                    e0 = e0 > 0.f ? e0 : 0.2f * e0;
                    e1 = e1 > 0.f ? e1 : 0.2f * e1;
                    den0 += __expf(e0);
                    den1 += __expf(e1);
                }
            }
            for (int o = 32; o > 0; o >>= 1) {
                den0 += __shfl_xor(den0, o);
                den1 += __shfl_xor(den1, o);
            }
            const float inv0 = 1.0f / den0, inv1 = 1.0f / den1;
            for (int c0 = beg; c0 < end; c0 += 64) {
                const int j = c0 + lane;
                uint sof = 0;
                float w0 = 0.f, w1 = 0.f;
                if (j < end) {
                    const int s = csrs[rel][j];
                    const float2 e = els[rel][s];
                    float e0 = e.x + erd.x, e1 = e.y + erd.y;
                    e0 = e0 > 0.f ? e0 : 0.2f * e0;
                    e1 = e1 > 0.f ? e1 : 0.2f * e1;
                    w0 = __expf(e0) * inv0;
                    w1 = __expf(e1) * inv1;
                    sof = (uint)s << 8;
                }
                wo[wid][0][lane] = make_uint2(sof, __float_as_uint(w0));
                wo[wid][1][lane] = make_uint2(sof, __float_as_uint(w1));
                const int cl = min(64, end - c0);
                const int dp = (cl + 1) & ~1;
                for (int tt = 0; tt < dp; tt += 2) {
                    const uint2 ow = wop[tt];
                    const float wgt = __uint_as_float(ow.y);
                    const uint2 u = *(const uint2*)(fgb + (ow.x + laneoff));
                    const float2 lo = bfpair(u.x), hi = bfpair(u.y);
                    a4.x += lo.x * wgt; a4.y += lo.y * wgt;
                    a4.z += hi.x * wgt; a4.w += hi.y * wgt;
                }
            }
        }

        // combine the two half-wave edge partitions (same dims, different edges)
        a4.x += __shfl_xor(a4.x, 32);
        a4.y += __shfl_xor(a4.y, 32);
        a4.z += __shfl_xor(a4.z, 32);
        a4.w += __shfl_xor(a4.w, 32);

        const float4 bv = *(const float4*)(biases[rel] + 4 * (lane & 31));
        o4.x += elu(a4.x + bv.x);
        o4.y += elu(a4.y + bv.y);
        o4.z += elu(a4.z + bv.z);
        o4.w += elu(a4.w + bv.w);
    }

    if (lane < 32) {
        if (obf) {
            ushort tmp[4] = { f2bf(o4.x), f2bf(o4.y), f2bf(o4.z), f2bf(o4.w) };
            *(uint2*)(outbf + (size_t)wv * DIM + 4 * lane) = *(const uint2*)tmp;
        } else {
            *(float4*)(outf + (size_t)wv * DIM + 4 * lane) = o4;
        }
    }
}

extern "C" void kernel_launch(void* const* d_in, const int* in_sizes, int n_in,
                              void* d_out, int out_size, void* d_ws, size_t ws_size,
                              hipStream_t stream)
{
    const float* x   = (const float*)d_in[0];
    const float* W0  = (const float*)d_in[1];
    const float* al0 = (const float*)d_in[2];
    const float* ar0 = (const float*)d_in[3];
    const float* b0  = (const float*)d_in[4];
    const float* W1  = (const float*)d_in[5];
    const float* al1 = (const float*)d_in[6];
    const float* ar1 = (const float*)d_in[7];
    const float* b1  = (const float*)d_in[8];
    const int* src0 = (const int*)d_in[9];
    const int* dst0 = (const int*)d_in[10];
    const int* src1 = (const int*)d_in[11];
    const int* dst1 = (const int*)d_in[12];
    float* out = (float*)d_out;

    char* w = (char*)d_ws;
    auto alloc = [&](size_t bytes) {
        char* p = w; w += (bytes + 255) & ~(size_t)255; return p;
    };
    ushort* h1bf   = (ushort*)alloc((size_t)NN * DIM * 2);
    ushort* fg0    = (ushort*)alloc((size_t)NN * DIM * 2);
    ushort* fg1    = (ushort*)alloc((size_t)NN * DIM * 2);
    ushort* WT     = (ushort*)alloc((size_t)4 * DIM * DIM * 2);
    float*  elb    = (float*)alloc((size_t)8 * NN * 4);      // el0,er0,el1,er1
    int*    row    = (int*)alloc((size_t)4 * (NN + 1) * 4);
    ushort* csr    = (ushort*)alloc((size_t)4 * NE * 2);
    uint*   binned = (uint*)alloc((size_t)4 * NB * CAP * 4); // slotted
    int*    bbase  = (int*)alloc((size_t)4 * (NB + 1) * 4);
    int*    gcur   = (int*)alloc((size_t)4 * NB * 4);

    // ---- one-time prep ----
    conv_wt<<<64, 256, 0, stream>>>(W0, W1, WT);
    init_gcur<<<1, 512, 0, stream>>>(gcur);
    {
        const int bpset = (NE + CH - 1) / CH;
        bin_edges<<<4 * bpset, 256, 0, stream>>>(dst0, dst1, src0, src1, gcur, binned);
    }
    scan_buckets<<<1, 64, 0, stream>>>(gcur, bbase, row);
    build_csr<<<4 * NB, 256, 0, stream>>>(bbase, binned, row, csr);

    const int gblocks = (NN + 63) / 64;
    for (int L = 0; L < 2; L++) {
        const ushort* WTl = WT + (size_t)L * 2 * DIM * DIM;
        const float* al  = L ? al1 : al0;
        const float* ar  = L ? ar1 : ar0;
        const float* b   = L ? b1 : b0;
        gemm_dual<<<gblocks, 256, 0, stream>>>(
            L ? h1bf : nullptr, L ? nullptr : x, WTl, al, ar,
            fg0, fg1, elb, NN, L ? 0 : 1);
        const int es0 = L * 2, es1 = L * 2 + 1;
        float* el0p = elb;
        float* er0p = elb + (size_t)NN * 2;
        float* el1p = elb + (size_t)NN * 4;
        float* er1p = elb + (size_t)NN * 6;
        aggregate_dual<<<(NN * 64 + 255) / 256, 256, 0, stream>>>(
            row + es0 * (NN + 1), csr + (size_t)es0 * NE,
            row + es1 * (NN + 1), csr + (size_t)es1 * NE,
            (const float2*)el0p, (const float2*)er0p,
            (const float2*)el1p, (const float2*)er1p,
            fg0, fg1, b, b + DIM,
            L ? out : nullptr, L ? nullptr : h1bf, L ? 0 : 1);
    }
}

// Round 2
// 354.951 us; speedup vs baseline: 1.0515x; 1.0336x over previous
//
#include <hip/hip_runtime.h>

#define NN 50000
#define NE 800000
#define DIM 128
#define NB 128          // dst buckets for binned CSR build
#define CH 4096         // edges per binning block
#define CAP 8192        // slots per bucket (mean 6250, sd 79 -> +24 sigma)

typedef unsigned int uint;
typedef unsigned short ushort;
typedef __attribute__((ext_vector_type(8))) short v8s;
typedef __attribute__((ext_vector_type(4))) float v4f;

__device__ __forceinline__ ushort f2bf(float f) {
    union { float f; uint i; } c; c.f = f;
    const uint r = (c.i + 0x7fffu + ((c.i >> 16) & 1u)) >> 16;
    return (ushort)r;
}

// WT[m][n][k] = bf16(W[m][k][n]); m: 0,1 from W0, 2,3 from W1.
__global__ __launch_bounds__(256) void conv_wt(
    const float* __restrict__ W0, const float* __restrict__ W1,
    ushort* __restrict__ WT)
{
    const int t = blockIdx.x * 256 + threadIdx.x;
#pragma unroll
    for (int i = 0; i < 4; i++) {
        const int o = t * 4 + i;                    // 0 .. 65535
        const int m = o >> 14, rem = o & 16383;
        const int nrow = rem >> 7, k = rem & 127;
        const float* src = (m < 2) ? (W0 + (size_t)m * 16384)
                                   : (W1 + (size_t)(m - 2) * 16384);
        WT[o] = f2bf(src[k * 128 + nrow]);
    }
}

// ---------------- dual-relation MFMA GEMM ----------------
// Block 256 = 4 waves; wave w: rows [b*64+16w,+16) x 128 cols, both relations.
// A loaded once (f32 path converts in-register). Epilogue: LDS-staged
// coalesced bf16 store + fused el/er reduction.
__global__ __launch_bounds__(256) void gemm_dual(
    const ushort* __restrict__ hbf, const float* __restrict__ xf,
    const ushort* __restrict__ WT,
    const float* __restrict__ al, const float* __restrict__ ar,
    ushort* __restrict__ fg0, ushort* __restrict__ fg1,
    float* __restrict__ elb, int n, int is_f32)
{
    __shared__ ushort tile[64][136];
    const int tid = threadIdx.x;
    const int w = tid >> 6, lane = tid & 63;
    const int quad = lane >> 4, l16 = lane & 15;
    const int row0 = blockIdx.x * 64 + w * 16;

    int arow = row0 + l16;
    if (arow >= n) arow = n - 1;   // clamp; OOB rows never stored

    v8s afr[4];
    if (is_f32) {
        const float* ap = xf + (size_t)arow * DIM + quad * 8;
#pragma unroll
        for (int kt = 0; kt < 4; kt++) {
            const float4 a0 = *(const float4*)(ap + kt * 32);
            const float4 a1 = *(const float4*)(ap + kt * 32 + 4);
            ushort tmp[8] = { f2bf(a0.x), f2bf(a0.y), f2bf(a0.z), f2bf(a0.w),
                              f2bf(a1.x), f2bf(a1.y), f2bf(a1.z), f2bf(a1.w) };
            afr[kt] = *(const v8s*)tmp;
        }
    } else {
        const ushort* ap = hbf + (size_t)arow * DIM + quad * 8;
#pragma unroll
        for (int kt = 0; kt < 4; kt++) afr[kt] = *(const v8s*)(ap + kt * 32);
    }

    for (int rel = 0; rel < 2; rel++) {
        const ushort* bp = WT + (size_t)rel * DIM * DIM + (size_t)l16 * DIM + quad * 8;
        v4f acc[8];
#pragma unroll
        for (int nt = 0; nt < 8; nt++) acc[nt] = (v4f)0.0f;
#pragma unroll
        for (int kt = 0; kt < 4; kt++) {
#pragma unroll
            for (int nt = 0; nt < 8; nt++) {
                const v8s b = *(const v8s*)(bp + (size_t)nt * 16 * DIM + kt * 32);
                acc[nt] = __builtin_amdgcn_mfma_f32_16x16x32_bf16(afr[kt], b, acc[nt], 0, 0, 0);
            }
        }

        // el/er: partial dot per lane, reduce across l16 within quad rows
        const float* alr = al + rel * DIM;
        const float* arr = ar + rel * DIM;
        float pel[4][2], per2[4][2];
#pragma unroll
        for (int r = 0; r < 4; r++)
            pel[r][0] = pel[r][1] = per2[r][0] = per2[r][1] = 0.f;
#pragma unroll
        for (int nt = 0; nt < 8; nt++) {
            const int col = nt * 16 + l16;
            const float av = alr[col], rv = arr[col];
            const int head = nt >> 2;
#pragma unroll
            for (int r = 0; r < 4; r++) {
                pel[r][head] += acc[nt][r] * av;
                per2[r][head] += acc[nt][r] * rv;
            }
        }
#pragma unroll
        for (int o = 1; o < 16; o <<= 1) {
#pragma unroll
            for (int r = 0; r < 4; r++) {
#pragma unroll
                for (int h = 0; h < 2; h++) {
                    pel[r][h] += __shfl_xor(pel[r][h], o);
                    per2[r][h] += __shfl_xor(per2[r][h], o);
                }
            }
        }
        float* elp = elb + (size_t)rel * NN * 4;
        float* erp = elp + (size_t)NN * 2;
        if (l16 == 0) {
#pragma unroll
            for (int r = 0; r < 4; r++) {
                const int row = row0 + quad * 4 + r;
                if (row < n) {
#pragma unroll
                    for (int h = 0; h < 2; h++) {
                        elp[row * 2 + h] = pel[r][h];
                        erp[row * 2 + h] = per2[r][h];
                    }
                }
            }
        }

        // coalesced bf16 store via LDS
        __syncthreads();   // prior rel's tile reads done
        const int lr0 = w * 16 + quad * 4;
#pragma unroll
        for (int nt = 0; nt < 8; nt++) {
            const int col = nt * 16 + l16;
#pragma unroll
            for (int r = 0; r < 4; r++)
                tile[lr0 + r][col] = f2bf(acc[nt][r]);
        }
        __syncthreads();
        ushort* fgr = rel ? fg1 : fg0;
        const int srow = tid >> 2, ch = tid & 3;   // 64 rows x 4 chunks of 32
        const int grow = blockIdx.x * 64 + srow;
        if (grow < n) {
            const uint4* lp = (const uint4*)&tile[srow][ch * 32];
            uint4* gp = (uint4*)(fgr + (size_t)grow * DIM + ch * 32);
            gp[0] = lp[0];
            gp[1] = lp[1];
            gp[2] = lp[2];
            gp[3] = lp[3];
        }
    }
}

// ---------------- CSR build (fixed-capacity buckets) ----------------
__global__ __launch_bounds__(512) void init_gcur(int* __restrict__ gcur)
{
    const int i = threadIdx.x;
    gcur[i] = i * CAP;
}

// Pass A: bin edges by dst bucket; payload packed (dst<<16)|src.
__global__ __launch_bounds__(256) void bin_edges(
    const int* __restrict__ dst0, const int* __restrict__ dst1,
    const int* __restrict__ src0, const int* __restrict__ src1,
    int* __restrict__ gcur, uint* __restrict__ binned)
{
    __shared__ int hist[NB], ebase[NB], lcur[NB], gbase[NB], sc[NB];
    __shared__ uint stage[CH];
    const int bpset = (NE + CH - 1) / CH;
    const int bid = blockIdx.x;
    const int s = bid / bpset, cb = bid - s * bpset;
    const int* dstp = (s < 2) ? (dst0 + (size_t)s * NE) : (dst1 + (size_t)(s - 2) * NE);
    const int* srcp = (s < 2) ? (src0 + (size_t)s * NE) : (src1 + (size_t)(s - 2) * NE);
    const int e0 = cb * CH;
    const int t = threadIdx.x;

    if (t < NB) hist[t] = 0;
    __syncthreads();

    int myd[16], mys[16];
#pragma unroll
    for (int k = 0; k < 16; k++) {
        const int e = e0 + t + k * 256;
        if (e < NE) {
            const int d = dstp[e];
            myd[k] = d;
            mys[k] = srcp[e];
            atomicAdd(&hist[(d * NB) / NN], 1);
        } else myd[k] = -1;
    }
    __syncthreads();
    if (t < NB) sc[t] = hist[t];
    __syncthreads();
    for (int o = 1; o < NB; o <<= 1) {
        int tv = 0;
        if (t < NB && t >= o) tv = sc[t - o];
        __syncthreads();
        if (t < NB) sc[t] += tv;
        __syncthreads();
    }
    if (t < NB) {
        ebase[t] = sc[t] - hist[t];
        lcur[t]  = sc[t] - hist[t];
        gbase[t] = atomicAdd(&gcur[s * NB + t], hist[t]);
    }
    __syncthreads();
#pragma unroll
    for (int k = 0; k < 16; k++) {
        if (myd[k] >= 0) {
            const int b = (myd[k] * NB) / NN;
            const int p = atomicAdd(&lcur[b], 1);
            stage[p] = ((uint)myd[k] << 16) | (uint)mys[k];
        }
    }
    __syncthreads();
    const int total = ebase[NB - 1] + hist[NB - 1];
    for (int i = t; i < total; i += 256) {
        const uint v = stage[i];
        const int b = ((int)(v >> 16) * NB) / NN;
        binned[gbase[b] + (i - ebase[b])] = v;   // gbase is absolute (slotted)
    }
}

// post-scan: packed per-set bucket bases from gcur fill levels.
__global__ __launch_bounds__(64) void scan_buckets(
    const int* __restrict__ gcur, int* __restrict__ bbase, int* __restrict__ row)
{
    const int s = threadIdx.x;
    if (s < 4) {
        int acc = 0;
        for (int b = 0; b < NB; b++) {
            bbase[s * (NB + 1) + b] = acc;
            acc += gcur[s * NB + b] - (s * NB + b) * CAP;
        }
        bbase[s * (NB + 1) + NB] = acc;   // == NE
        row[s * (NN + 1) + NN] = NE;
    }
}

// Pass B: per (set,bucket): LDS degree count + scan -> row[] + ushort csr.
__global__ __launch_bounds__(256) void build_csr(
    const int* __restrict__ bbase, const uint* __restrict__ binned,
    int* __restrict__ row, ushort* __restrict__ csr_src)
{
    __shared__ int A[512], B[512], lcur[512];
    const int bid = blockIdx.x;
    const int s = bid >> 7, b = bid & (NB - 1);
    const int nb0 = (b * NN + NB - 1) / NB;
    int nb1 = ((b + 1) * NN + NB - 1) / NB;
    if (nb1 > NN) nb1 = NN;
    const int nloc = nb1 - nb0;
    const int jb = bbase[s * (NB + 1) + b], je = bbase[s * (NB + 1) + b + 1];
    const int cnt = je - jb;
    const uint* bslot = binned + (size_t)(s * NB + b) * CAP;
    const int t = threadIdx.x;

    A[t] = 0; A[t + 256] = 0;
    __syncthreads();
    for (int j = t; j < cnt; j += 256)
        atomicAdd(&A[(int)(bslot[j] >> 16) - nb0], 1);
    __syncthreads();
    const int c0 = A[t], c1 = A[t + 256];
    int* cur = A; int* nxt = B;
    for (int off = 1; off < 512; off <<= 1) {
        nxt[t]       = cur[t]       + ((t >= off)       ? cur[t - off]       : 0);
        nxt[t + 256] = cur[t + 256] + ((t + 256 >= off) ? cur[t + 256 - off] : 0);
        __syncthreads();
        int* tmp = cur; cur = nxt; nxt = tmp;
    }
    if (t < nloc) {
        const int v = jb + cur[t] - c0;
        lcur[t] = v;
        row[s * (NN + 1) + nb0 + t] = v;
    }
    if (t + 256 < nloc) {
        const int v = jb + cur[t + 256] - c1;
        lcur[t + 256] = v;
        row[s * (NN + 1) + nb0 + t + 256] = v;
    }
    __syncthreads();
    ushort* outp = csr_src + (size_t)s * NE;
    for (int j = t; j < cnt; j += 256) {
        const uint v = bslot[j];
        const int p = atomicAdd(&lcur[(int)(v >> 16) - nb0], 1);
        outp[p] = (ushort)(v & 0xffffu);
    }
}

__device__ __forceinline__ float elu(float v) { return v > 0.f ? v : expm1f(v); }
__device__ __forceinline__ float2 bfpair(uint u) {
    union { uint i; float f; } lo, hi;
    lo.i = u << 16;
    hi.i = u & 0xffff0000u;
    return make_float2(lo.f, hi.f);
}

// ---------------- dual-relation fused softmax + aggregate -------------------
// One wave per dst node; lane owns dims (2*lane, 2*lane+1) of the output.
// All 64 LDS weight/offset slots are written (zero weight beyond deg), so the
// gather loop runs over deg padded up to a multiple of 16 with a fully
// unrolled 16-edge body: 16 ds_reads + 16 addr + 16 global_load_dword issued
// back-to-back -> ~16 gathers in flight per wave (vs ~4 with unroll-4),
// attacking the L2/L3 gather latency that bounds this kernel.
__global__ __launch_bounds__(256) void aggregate_dual(
    const int* __restrict__ row0, const ushort* __restrict__ csr0,
    const int* __restrict__ row1, const ushort* __restrict__ csr1,
    const float2* __restrict__ el0, const float2* __restrict__ er0,
    const float2* __restrict__ el1, const float2* __restrict__ er1,
    const ushort* __restrict__ fg0, const ushort* __restrict__ fg1,
    const float* __restrict__ bias0, const float* __restrict__ bias1,
    float* __restrict__ outf, ushort* __restrict__ outbf, int obf)
{
    __shared__ uint soff[4][64];
    __shared__ float wts[4][2][64];
    const int wv = (blockIdx.x * 256 + threadIdx.x) >> 6;
    if (wv >= NN) return;
    const int lane = threadIdx.x & 63;
    const int wid = threadIdx.x >> 6;

    const int* rows[2] = {row0, row1};
    const ushort* csrs[2] = {csr0, csr1};
    const float2* els[2] = {el0, el1};
    const float2* ers[2] = {er0, er1};
    const ushort* fgs[2] = {fg0, fg1};
    const float* biases[2] = {bias0, bias1};

    float oacc0 = 0.f, oacc1 = 0.f;

#pragma unroll
    for (int rel = 0; rel < 2; rel++) {
        const int beg = rows[rel][wv], end = rows[rel][wv + 1];
        const int deg = end - beg;
        const float2 erd = ers[rel][wv];
        float2 acc = make_float2(0.f, 0.f);

        if (deg <= 64) {
            uint sof = 0;
            float ex0 = 0.f, ex1 = 0.f;
            if (lane < deg) {
                const int s = csrs[rel][beg + lane];
                const float2 e = els[rel][s];
                float e0 = e.x + erd.x, e1 = e.y + erd.y;
                e0 = e0 > 0.f ? e0 : 0.2f * e0;
                e1 = e1 > 0.f ? e1 : 0.2f * e1;
                ex0 = __expf(e0);
                ex1 = __expf(e1);
                sof = (uint)s << 8;
            }
            float den0 = ex0, den1 = ex1;
            for (int o = 32; o > 0; o >>= 1) {
                den0 += __shfl_xor(den0, o);
                den1 += __shfl_xor(den1, o);
            }
            const float inv0 = 1.0f / den0, inv1 = 1.0f / den1;
            soff[wid][lane] = sof;
            wts[wid][0][lane] = ex0 * inv0;   // 0 for lane >= deg
            wts[wid][1][lane] = ex1 * inv1;
            const char* fgb = (const char*)fgs[rel] + lane * 4;
            const float* wrow = wts[wid][lane >> 5];
            const uint* sorow = soff[wid];
            const int dp = (deg + 15) & ~15;   // pad slots: w=0, sof=0 (row 0)
            for (int tt = 0; tt < dp; tt += 16) {
                uint off[16];
                float wgt[16];
#pragma unroll
                for (int k = 0; k < 16; k++) {
                    off[k] = sorow[tt + k];
                    wgt[k] = wrow[tt + k];
                }
                uint u[16];
#pragma unroll
                for (int k = 0; k < 16; k++)
                    u[k] = *(const uint*)(fgb + off[k]);
#pragma unroll
                for (int k = 0; k < 16; k++) {
                    const float2 f = bfpair(u[k]);
                    acc.x += f.x * wgt[k];
                    acc.y += f.y * wgt[k];
                }
            }
        } else {
            // (statistically dead for Poisson(16) degrees; kept for safety)
            float den0 = 0.f, den1 = 0.f;
            for (int c0 = beg; c0 < end; c0 += 64) {
                const int j = c0 + lane;
                if (j < end) {
                    const float2 e = els[rel][csrs[rel][j]];
                    float e0 = e.x + erd.x, e1 = e.y + erd.y;
                    e0 = e0 > 0.f ? e0 : 0.2f * e0;
                    e1 = e1 > 0.f ? e1 : 0.2f * e1;
                    den0 += __expf(e0);
                    den1 += __expf(e1);
                }
            }
            for (int o = 32; o > 0; o >>= 1) {
                den0 += __shfl_xor(den0, o);
                den1 += __shfl_xor(den1, o);
            }
            const float inv0 = 1.0f / den0, inv1 = 1.0f / den1;
            for (int c0 = beg; c0 < end; c0 += 64) {
                const int j = c0 + lane;
                int s = -1;
                float ex0 = 0.f, ex1 = 0.f;
                if (j < end) {
                    s = csrs[rel][j];
                    const float2 e = els[rel][s];
                    float e0 = e.x + erd.x, e1 = e.y + erd.y;
                    e0 = e0 > 0.f ? e0 : 0.2f * e0;
                    e1 = e1 > 0.f ? e1 : 0.2f * e1;
                    ex0 = __expf(e0) * inv0;
                    ex1 = __expf(e1) * inv1;
                }
                const int cm = min(64, end - c0);
                for (int tt = 0; tt < cm; tt++) {
                    const int st = __shfl(s, tt);
                    const float a0 = __shfl(ex0, tt);
                    const float a1 = __shfl(ex1, tt);
                    const float aa = (lane < 32) ? a0 : a1;
                    const float2 fv = bfpair(
                        *(const uint*)((const char*)fgs[rel] + ((size_t)st << 8) + lane * 4));
                    acc.x += fv.x * aa;
                    acc.y += fv.y * aa;
                }
            }
        }

        const float b0 = biases[rel][2 * lane], b1 = biases[rel][2 * lane + 1];
        oacc0 += elu(acc.x + b0);
        oacc1 += elu(acc.y + b1);
    }

    if (obf) {
        ushort tmp[2] = { f2bf(oacc0), f2bf(oacc1) };
        *(uint*)(outbf + (size_t)wv * DIM + 2 * lane) = *(const uint*)tmp;
    } else {
        float* op = outf + (size_t)wv * DIM + 2 * lane;
        op[0] = oacc0; op[1] = oacc1;
    }
}

extern "C" void kernel_launch(void* const* d_in, const int* in_sizes, int n_in,
                              void* d_out, int out_size, void* d_ws, size_t ws_size,
                              hipStream_t stream)
{
    const float* x   = (const float*)d_in[0];
    const float* W0  = (const float*)d_in[1];
    const float* al0 = (const float*)d_in[2];
    const float* ar0 = (const float*)d_in[3];
    const float* b0  = (const float*)d_in[4];
    const float* W1  = (const float*)d_in[5];
    const float* al1 = (const float*)d_in[6];
    const float* ar1 = (const float*)d_in[7];
    const float* b1  = (const float*)d_in[8];
    const int* src0 = (const int*)d_in[9];
    const int* dst0 = (const int*)d_in[10];
    const int* src1 = (const int*)d_in[11];
    const int* dst1 = (const int*)d_in[12];
    float* out = (float*)d_out;

    char* w = (char*)d_ws;
    auto alloc = [&](size_t bytes) {
        char* p = w; w += (bytes + 255) & ~(size_t)255; return p;
    };
    ushort* h1bf   = (ushort*)alloc((size_t)NN * DIM * 2);
    ushort* fg0    = (ushort*)alloc((size_t)NN * DIM * 2);
    ushort* fg1    = (ushort*)alloc((size_t)NN * DIM * 2);
    ushort* WT     = (ushort*)alloc((size_t)4 * DIM * DIM * 2);
    float*  elb    = (float*)alloc((size_t)8 * NN * 4);      // el0,er0,el1,er1
    int*    row    = (int*)alloc((size_t)4 * (NN + 1) * 4);
    ushort* csr    = (ushort*)alloc((size_t)4 * NE * 2);
    uint*   binned = (uint*)alloc((size_t)4 * NB * CAP * 4); // slotted
    int*    bbase  = (int*)alloc((size_t)4 * (NB + 1) * 4);
    int*    gcur   = (int*)alloc((size_t)4 * NB * 4);

    // ---- one-time prep ----
    conv_wt<<<64, 256, 0, stream>>>(W0, W1, WT);
    init_gcur<<<1, 512, 0, stream>>>(gcur);
    {
        const int bpset = (NE + CH - 1) / CH;
        bin_edges<<<4 * bpset, 256, 0, stream>>>(dst0, dst1, src0, src1, gcur, binned);
    }
    scan_buckets<<<1, 64, 0, stream>>>(gcur, bbase, row);
    build_csr<<<4 * NB, 256, 0, stream>>>(bbase, binned, row, csr);

    const int gblocks = (NN + 63) / 64;
    for (int L = 0; L < 2; L++) {
        const ushort* WTl = WT + (size_t)L * 2 * DIM * DIM;
        const float* al  = L ? al1 : al0;
        const float* ar  = L ? ar1 : ar0;
        const float* b   = L ? b1 : b0;
        gemm_dual<<<gblocks, 256, 0, stream>>>(
            L ? h1bf : nullptr, L ? nullptr : x, WTl, al, ar,
            fg0, fg1, elb, NN, L ? 0 : 1);
        const int es0 = L * 2, es1 = L * 2 + 1;
        float* el0p = elb;
        float* er0p = elb + (size_t)NN * 2;
        float* el1p = elb + (size_t)NN * 4;
        float* er1p = elb + (size_t)NN * 6;
        aggregate_dual<<<(NN * 64 + 255) / 256, 256, 0, stream>>>(
            row + es0 * (NN + 1), csr + (size_t)es0 * NE,
            row + es1 * (NN + 1), csr + (size_t)es1 * NE,
            (const float2*)el0p, (const float2*)er0p,
            (const float2*)el1p, (const float2*)er1p,
            fg0, fg1, b, b + DIM,
            L ? out : nullptr, L ? nullptr : h1bf, L ? 0 : 1);
    }
}